// Round 1
// baseline (1499.750 us; speedup 1.0000x reference)
//
#include <hip/hip_runtime.h>
#include <cstddef>

#define D 64

// ---------------------------------------------------------------------------
// init: e_cur = acc = concat(emb_user, emb_item)
// ---------------------------------------------------------------------------
__global__ void init_kernel(const float* __restrict__ eu, const float* __restrict__ ei,
                            float* __restrict__ e_cur, float* __restrict__ acc,
                            int nd_user, int nd_total) {
    int i = blockIdx.x * blockDim.x + threadIdx.x;
    int stride = gridDim.x * blockDim.x;
    int nq = nd_total >> 2;       // float4 count
    int nq_user = nd_user >> 2;
    for (int idx = i; idx < nq; idx += stride) {
        float4 v;
        if (idx < nq_user) v = ((const float4*)eu)[idx];
        else               v = ((const float4*)ei)[idx - nq_user];
        ((float4*)e_cur)[idx] = v;
        ((float4*)acc)[idx]   = v;
    }
}

// ---------------------------------------------------------------------------
// spmm: y[row[e]] += val[e] * x[col[e]]   (one wave per edge, lane = dim)
// ---------------------------------------------------------------------------
__global__ void spmm_kernel(const int* __restrict__ row, const int* __restrict__ col,
                            const float* __restrict__ val, const float* __restrict__ x,
                            float* __restrict__ y, int nnz) {
    int lane  = threadIdx.x & 63;
    int wave  = (blockIdx.x * blockDim.x + threadIdx.x) >> 6;
    int nwave = (gridDim.x * blockDim.x) >> 6;
    for (int e = wave; e < nnz; e += nwave) {
        int   r = row[e];
        int   c = col[e];
        float v = val[e];
        float xv = x[(size_t)c * D + lane];
        atomicAdd(&y[(size_t)r * D + lane], v * xv);
    }
}

// ---------------------------------------------------------------------------
// accum: acc += e_next
// ---------------------------------------------------------------------------
__global__ void accum_kernel(float* __restrict__ acc, const float* __restrict__ nxt,
                             int nd_total) {
    int i = blockIdx.x * blockDim.x + threadIdx.x;
    int stride = gridDim.x * blockDim.x;
    int nq = nd_total >> 2;
    for (int idx = i; idx < nq; idx += stride) {
        float4 a = ((float4*)acc)[idx];
        float4 b = ((const float4*)nxt)[idx];
        a.x += b.x; a.y += b.y; a.z += b.z; a.w += b.w;
        ((float4*)acc)[idx] = a;
    }
}

// ---------------------------------------------------------------------------
// head: per b — two 64x64 GEMVs, softmax, sigmoid, weighted dot
// one wave per b; W staged transposed in LDS (conflict-free lane-j access)
// ---------------------------------------------------------------------------
__global__ __launch_bounds__(256)
void head_kernel(const float* __restrict__ acc,
                 const float* __restrict__ wu, const float* __restrict__ wi,
                 const float* __restrict__ x1, const float* __restrict__ x0,
                 const int* __restrict__ users, const int* __restrict__ items,
                 const int* __restrict__ xij,
                 float* __restrict__ out, int B, int n_users) {
    __shared__ float wtu[D * D];   // wtu[k*64 + j] = w_user[j][k]
    __shared__ float wti[D * D];
    for (int idx = threadIdx.x; idx < D * D; idx += blockDim.x) {
        int j = idx >> 6, k = idx & 63;
        wtu[k * D + j] = wu[idx];
        wti[k * D + j] = wi[idx];
    }
    __syncthreads();

    int lane = threadIdx.x & 63;
    int wid  = threadIdx.x >> 6;
    int nw   = blockDim.x >> 6;

    for (int b = blockIdx.x * nw + wid; b < B; b += gridDim.x * nw) {
        int u  = users[b];
        int it = items[b];
        float ue = acc[(size_t)u * D + lane] * 0.25f;
        float ie = acc[(size_t)(n_users + it) * D + lane] * 0.25f;

        float su = 0.f, si = 0.f;
        #pragma unroll 8
        for (int k = 0; k < D; ++k) {
            float uk = __shfl(ue, k);
            float ik = __shfl(ie, k);
            su = fmaf(uk, wtu[k * D + lane], su);
            si = fmaf(ik, wti[k * D + lane], si);
        }

        // softmax over su (64 lanes)
        float m = su;
        for (int off = 32; off > 0; off >>= 1) m = fmaxf(m, __shfl_xor(m, off));
        float p = __expf(su - m);
        float s = p;
        for (int off = 32; off > 0; off >>= 1) s += __shfl_xor(s, off);
        float soft = p / s;

        float sig  = 1.f / (1.f + __expf(-si));
        float term = 0.5f * soft * sig;
        for (int off = 32; off > 0; off >>= 1) term += __shfl_xor(term, off);

        if (lane == 0) {
            float xe   = (xij[b] > 0) ? x1[it] : x0[it];
            float sigx = 1.f / (1.f + __expf(-xe));
            out[b] = term + 0.5f * sigx;
        }
    }
}

// ---------------------------------------------------------------------------
extern "C" void kernel_launch(void* const* d_in, const int* in_sizes, int n_in,
                              void* d_out, int out_size, void* d_ws, size_t ws_size,
                              hipStream_t stream) {
    const float* emb_user = (const float*)d_in[0];
    const float* emb_item = (const float*)d_in[1];
    const float* w_user   = (const float*)d_in[2];
    const float* w_item   = (const float*)d_in[3];
    const float* xij_emb1 = (const float*)d_in[4];
    const float* xij_emb0 = (const float*)d_in[5];
    const float* g_val    = (const float*)d_in[6];
    const int*   g_row    = (const int*)d_in[7];
    const int*   g_col    = (const int*)d_in[8];
    const int*   users    = (const int*)d_in[9];
    const int*   items    = (const int*)d_in[10];
    const int*   xij      = (const int*)d_in[11];
    float*       out      = (float*)d_out;

    const int n_users = in_sizes[0] / D;     // 100000
    const int n_items = in_sizes[1] / D;     // 50000
    const int n_total = n_users + n_items;   // 150000
    const int nnz     = in_sizes[6];         // 2000000
    const int B       = in_sizes[9];         // 16384

    const int nd_user  = n_users * D;
    const int nd_total = n_total * D;
    const size_t bytes = (size_t)nd_total * sizeof(float);

    float* e_cur = (float*)d_ws;
    float* e_nxt = (float*)((char*)d_ws + bytes);
    float* acc   = (float*)((char*)d_ws + 2 * bytes);

    // init
    init_kernel<<<4096, 256, 0, stream>>>(emb_user, emb_item, e_cur, acc,
                                          nd_user, nd_total);

    // 3 propagation layers
    float* cur = e_cur;
    float* nxt = e_nxt;
    for (int l = 0; l < 3; ++l) {
        hipMemsetAsync(nxt, 0, bytes, stream);
        spmm_kernel<<<2048, 256, 0, stream>>>(g_row, g_col, g_val, cur, nxt, nnz);
        accum_kernel<<<4096, 256, 0, stream>>>(acc, nxt, nd_total);
        float* t = cur; cur = nxt; nxt = t;
    }

    // head
    head_kernel<<<256, 256, 0, stream>>>(acc, w_user, w_item, xij_emb1, xij_emb0,
                                         users, items, xij, out, B, n_users);
}

// Round 2
// 692.401 us; speedup vs baseline: 2.1660x; 2.1660x over previous
//
#include <hip/hip_runtime.h>
#include <cstddef>

#define D 64
#define SCAN_B 256

// ---------------------------------------------------------------------------
// init: e_cur = acc = concat(emb_user, emb_item)
// ---------------------------------------------------------------------------
__global__ void init_kernel(const float* __restrict__ eu, const float* __restrict__ ei,
                            float* __restrict__ e_cur, float* __restrict__ acc,
                            int nd_user, int nd_total) {
    int i = blockIdx.x * blockDim.x + threadIdx.x;
    int stride = gridDim.x * blockDim.x;
    int nq = nd_total >> 2;
    int nq_user = nd_user >> 2;
    for (int idx = i; idx < nq; idx += stride) {
        float4 v;
        if (idx < nq_user) v = ((const float4*)eu)[idx];
        else               v = ((const float4*)ei)[idx - nq_user];
        ((float4*)e_cur)[idx] = v;
        ((float4*)acc)[idx]   = v;
    }
}

// ---------------------------------------------------------------------------
// CSR build: histogram -> scan -> scatter
// ---------------------------------------------------------------------------
__global__ void hist_kernel(const int* __restrict__ row, int* __restrict__ cnt, int nnz) {
    int i = blockIdx.x * blockDim.x + threadIdx.x;
    int stride = gridDim.x * blockDim.x;
    for (int e = i; e < nnz; e += stride) atomicAdd(&cnt[row[e]], 1);
}

// block-level exclusive scan; emits per-block totals
__global__ void scan1_kernel(const int* __restrict__ cnt, int* __restrict__ excl,
                             int* __restrict__ bsum, int n) {
    __shared__ int s[SCAN_B];
    int i = blockIdx.x * SCAN_B + threadIdx.x;
    int v = (i < n) ? cnt[i] : 0;
    s[threadIdx.x] = v;
    __syncthreads();
    for (int off = 1; off < SCAN_B; off <<= 1) {
        int t = (threadIdx.x >= (unsigned)off) ? s[threadIdx.x - off] : 0;
        __syncthreads();
        s[threadIdx.x] += t;
        __syncthreads();
    }
    if (i < n) excl[i] = s[threadIdx.x] - v;
    if (threadIdx.x == SCAN_B - 1) bsum[blockIdx.x] = s[threadIdx.x];
}

// single-block exclusive scan of block sums (nb <= 1024; here nb = 587)
__global__ void scan2_kernel(int* __restrict__ bsum, int nb) {
    __shared__ int s[1024];
    int v = (threadIdx.x < (unsigned)nb) ? bsum[threadIdx.x] : 0;
    s[threadIdx.x] = v;
    __syncthreads();
    for (int off = 1; off < 1024; off <<= 1) {
        int t = (threadIdx.x >= (unsigned)off) ? s[threadIdx.x - off] : 0;
        __syncthreads();
        s[threadIdx.x] += t;
        __syncthreads();
    }
    if (threadIdx.x < (unsigned)nb) bsum[threadIdx.x] = s[threadIdx.x] - v;
}

__global__ void scan3_kernel(const int* __restrict__ excl, const int* __restrict__ bsum,
                             int* __restrict__ ptr, int* __restrict__ cursor,
                             int n, int nnz) {
    int i = blockIdx.x * blockDim.x + threadIdx.x;
    if (i < n) {
        int p = excl[i] + bsum[i / SCAN_B];
        ptr[i] = p;
        cursor[i] = p;
    }
    if (i == 0) ptr[n] = nnz;
}

__global__ void scatter_kernel(const int* __restrict__ row, const int* __restrict__ col,
                               const float* __restrict__ val, int* __restrict__ cursor,
                               float2* __restrict__ edges, int nnz) {
    int i = blockIdx.x * blockDim.x + threadIdx.x;
    int stride = gridDim.x * blockDim.x;
    for (int e = i; e < nnz; e += stride) {
        int r = row[e];
        int p = atomicAdd(&cursor[r], 1);
        edges[p] = make_float2(__int_as_float(col[e]), val[e]);
    }
}

// ---------------------------------------------------------------------------
// gather spmm: 4 rows per wave, 16 lanes/row, float4 dims per lane.
// y[r] = sum val*x[col]; acc[r] += y[r]   (fused accumulate, no atomics)
// ---------------------------------------------------------------------------
__global__ __launch_bounds__(256)
void spmm_row_kernel(const int* __restrict__ ptr, const float2* __restrict__ edges,
                     const float* __restrict__ x, float* __restrict__ y,
                     float* __restrict__ acc, int n) {
    int lane = threadIdx.x & 63;
    int wid  = (blockIdx.x * blockDim.x + threadIdx.x) >> 6;
    int sub  = lane & 15;          // dim quad: dims [sub*4, sub*4+4)
    int rg   = lane >> 4;          // row within wave: 0..3
    int r    = wid * 4 + rg;
    if (r >= n) return;

    int beg = ptr[r], end = ptr[r + 1];
    float4 s = make_float4(0.f, 0.f, 0.f, 0.f);
    for (int e = beg; e < end; ++e) {
        float2 ev = edges[e];          // 16 lanes same addr -> broadcast
        int   c = __float_as_int(ev.x);
        float v = ev.y;
        float4 xv = ((const float4*)(x + (size_t)c * D))[sub];
        s.x = fmaf(v, xv.x, s.x);
        s.y = fmaf(v, xv.y, s.y);
        s.z = fmaf(v, xv.z, s.z);
        s.w = fmaf(v, xv.w, s.w);
    }
    size_t o = (size_t)r * D + sub * 4;
    ((float4*)(y + o))[0] = s;
    float4 a = ((const float4*)(acc + o))[0];
    a.x += s.x; a.y += s.y; a.z += s.z; a.w += s.w;
    ((float4*)(acc + o))[0] = a;
}

// ---------------------------------------------------------------------------
// fallback atomic spmm (used only if ws_size too small for CSR path)
// ---------------------------------------------------------------------------
__global__ void spmm_atomic_kernel(const int* __restrict__ row, const int* __restrict__ col,
                                   const float* __restrict__ val, const float* __restrict__ x,
                                   float* __restrict__ y, int nnz) {
    int lane  = threadIdx.x & 63;
    int wave  = (blockIdx.x * blockDim.x + threadIdx.x) >> 6;
    int nwave = (gridDim.x * blockDim.x) >> 6;
    for (int e = wave; e < nnz; e += nwave) {
        int   r = row[e];
        int   c = col[e];
        float v = val[e];
        atomicAdd(&y[(size_t)r * D + lane], v * x[(size_t)c * D + lane]);
    }
}

__global__ void accum_kernel(float* __restrict__ acc, const float* __restrict__ nxt,
                             int nd_total) {
    int i = blockIdx.x * blockDim.x + threadIdx.x;
    int stride = gridDim.x * blockDim.x;
    int nq = nd_total >> 2;
    for (int idx = i; idx < nq; idx += stride) {
        float4 a = ((float4*)acc)[idx];
        float4 b = ((const float4*)nxt)[idx];
        a.x += b.x; a.y += b.y; a.z += b.z; a.w += b.w;
        ((float4*)acc)[idx] = a;
    }
}

// ---------------------------------------------------------------------------
// head: per b — two 64x64 GEMVs, softmax, sigmoid, weighted dot
// ---------------------------------------------------------------------------
__global__ __launch_bounds__(256)
void head_kernel(const float* __restrict__ acc,
                 const float* __restrict__ wu, const float* __restrict__ wi,
                 const float* __restrict__ x1, const float* __restrict__ x0,
                 const int* __restrict__ users, const int* __restrict__ items,
                 const int* __restrict__ xij,
                 float* __restrict__ out, int B, int n_users) {
    __shared__ float wtu[D * D];   // wtu[k*64 + j] = w_user[j][k]
    __shared__ float wti[D * D];
    for (int idx = threadIdx.x; idx < D * D; idx += blockDim.x) {
        int j = idx >> 6, k = idx & 63;
        wtu[k * D + j] = wu[idx];
        wti[k * D + j] = wi[idx];
    }
    __syncthreads();

    int lane = threadIdx.x & 63;
    int wid  = threadIdx.x >> 6;
    int nw   = blockDim.x >> 6;

    for (int b = blockIdx.x * nw + wid; b < B; b += gridDim.x * nw) {
        int u  = users[b];
        int it = items[b];
        float ue = acc[(size_t)u * D + lane] * 0.25f;
        float ie = acc[(size_t)(n_users + it) * D + lane] * 0.25f;

        float su = 0.f, si = 0.f;
        #pragma unroll 8
        for (int k = 0; k < D; ++k) {
            float uk = __shfl(ue, k);
            float ik = __shfl(ie, k);
            su = fmaf(uk, wtu[k * D + lane], su);
            si = fmaf(ik, wti[k * D + lane], si);
        }

        float m = su;
        for (int off = 32; off > 0; off >>= 1) m = fmaxf(m, __shfl_xor(m, off));
        float p = __expf(su - m);
        float sden = p;
        for (int off = 32; off > 0; off >>= 1) sden += __shfl_xor(sden, off);
        float soft = p / sden;

        float sig  = 1.f / (1.f + __expf(-si));
        float term = 0.5f * soft * sig;
        for (int off = 32; off > 0; off >>= 1) term += __shfl_xor(term, off);

        if (lane == 0) {
            float xe   = (xij[b] > 0) ? x1[it] : x0[it];
            float sigx = 1.f / (1.f + __expf(-xe));
            out[b] = term + 0.5f * sigx;
        }
    }
}

// ---------------------------------------------------------------------------
extern "C" void kernel_launch(void* const* d_in, const int* in_sizes, int n_in,
                              void* d_out, int out_size, void* d_ws, size_t ws_size,
                              hipStream_t stream) {
    const float* emb_user = (const float*)d_in[0];
    const float* emb_item = (const float*)d_in[1];
    const float* w_user   = (const float*)d_in[2];
    const float* w_item   = (const float*)d_in[3];
    const float* xij_emb1 = (const float*)d_in[4];
    const float* xij_emb0 = (const float*)d_in[5];
    const float* g_val    = (const float*)d_in[6];
    const int*   g_row    = (const int*)d_in[7];
    const int*   g_col    = (const int*)d_in[8];
    const int*   users    = (const int*)d_in[9];
    const int*   items    = (const int*)d_in[10];
    const int*   xij      = (const int*)d_in[11];
    float*       out      = (float*)d_out;

    const int n_users = in_sizes[0] / D;     // 100000
    const int n_items = in_sizes[1] / D;     // 50000
    const int n_total = n_users + n_items;   // 150000
    const int nnz     = in_sizes[6];         // 2000000
    const int B       = in_sizes[9];         // 16384

    const int nd_user  = n_users * D;
    const int nd_total = n_total * D;
    const size_t fbytes = (size_t)nd_total * sizeof(float);   // 38.4 MB

    char* w = (char*)d_ws;
    float* e_cur = (float*)w;                 w += fbytes;
    float* e_nxt = (float*)w;                 w += fbytes;
    float* acc   = (float*)w;                 w += fbytes;

    const int nb = (n_total + SCAN_B - 1) / SCAN_B;   // 587
    const size_t ebytes   = (size_t)nnz * sizeof(float2);   // 16 MB
    const size_t ptrbytes = ((size_t)(n_total + 1) * 4 + 15) & ~(size_t)15;
    const size_t nbytes   = ((size_t)n_total * 4 + 15) & ~(size_t)15;
    const size_t bsbytes  = ((size_t)nb * 4 + 15) & ~(size_t)15;
    const size_t need = 3 * fbytes + ebytes + ptrbytes + 3 * nbytes + bsbytes + 256;

    init_kernel<<<2048, 256, 0, stream>>>(emb_user, emb_item, e_cur, acc,
                                          nd_user, nd_total);

    if (ws_size >= need) {
        // ---- CSR gather path ----
        float2* edges  = (float2*)w;          w += ebytes;
        int*    ptr    = (int*)w;             w += ptrbytes;
        int*    cnt    = (int*)w;             w += nbytes;   // also 'excl' target below
        int*    excl   = (int*)w;             w += nbytes;
        int*    bsum   = (int*)w;             w += bsbytes;
        int*    cursor = cnt;  // reuse cnt as cursor after scan consumes it

        hipMemsetAsync(cnt, 0, (size_t)n_total * 4, stream);
        hist_kernel<<<1024, 256, 0, stream>>>(g_row, cnt, nnz);
        scan1_kernel<<<nb, SCAN_B, 0, stream>>>(cnt, excl, bsum, n_total);
        scan2_kernel<<<1, 1024, 0, stream>>>(bsum, nb);
        scan3_kernel<<<nb, SCAN_B, 0, stream>>>(excl, bsum, ptr, cursor, n_total, nnz);
        scatter_kernel<<<1024, 256, 0, stream>>>(g_row, g_col, g_val, cursor, edges, nnz);

        float* cur = e_cur;
        float* nxt = e_nxt;
        const int nblk = (n_total * 16 + 255) / 256;   // 16 threads per row
        for (int l = 0; l < 3; ++l) {
            spmm_row_kernel<<<nblk, 256, 0, stream>>>(ptr, edges, cur, nxt, acc, n_total);
            float* t = cur; cur = nxt; nxt = t;
        }
    } else {
        // ---- fallback: atomic scatter path ----
        float* cur = e_cur;
        float* nxt = e_nxt;
        for (int l = 0; l < 3; ++l) {
            hipMemsetAsync(nxt, 0, fbytes, stream);
            spmm_atomic_kernel<<<2048, 256, 0, stream>>>(g_row, g_col, g_val, cur, nxt, nnz);
            accum_kernel<<<2048, 256, 0, stream>>>(acc, nxt, nd_total);
            float* t = cur; cur = nxt; nxt = t;
        }
    }

    head_kernel<<<256, 256, 0, stream>>>(acc, w_user, w_item, xij_emb1, xij_emb0,
                                         users, items, xij, out, B, n_users);
}